// Round 5
// baseline (135.045 us; speedup 1.0000x reference)
//
#include <hip/hip_runtime.h>
#include <math.h>

#define NS2 0.70710678118654752440f  // 1/sqrt(2)
#define NS3 0.57735026918962576451f  // 1/sqrt(3)
#define NS6 0.40824829046386301636f  // 1/sqrt(6)

typedef _Float16 f16;
typedef _Float16 f16x8 __attribute__((ext_vector_type(8)));
typedef float    f32x4 __attribute__((ext_vector_type(4)));

// ws layout: G_T tiled by k-eighth: [8][7][2816] f16 (315.4 KB total).
// Eighth e covers global k: A-part k in [e*1280, +1280) -> local j 0..1279,
// B-part k in [10240 + e*1536, +1536) -> local j 1280..2815.
#define EI 19712          // 7*2816 f16 per eighth

// ---------------------------------------------------------------------------
// prep: G_T build only. 352 blocks x 64 columns. 4 o-split threads per k
// (q = tid>>6), kl = tid&63. LDS: s_wo[1680] + s_red[4][64][8].
// (verbatim — correctness-verified)
// ---------------------------------------------------------------------------
__global__ __launch_bounds__(256) void prep_kernel(
    const float* __restrict__ W3_0, const float* __restrict__ W3_1,
    const float* __restrict__ W3_2, const float* __restrict__ Wout,
    f16* __restrict__ wsh)
{
    __shared__ __align__(16) float smem[3728];
    float* s_wo  = smem;            // Wout 240x7
    float* s_red = smem + 1680;     // [4][64][8] partials
    const int tid = threadIdx.x;
    for (int i = tid; i < 1680; i += 256) s_wo[i] = Wout[i];
    __syncthreads();
    const int kl = tid & 63, q = tid >> 6;
    const int k  = blockIdx.x * 64 + kl;       // 0..22527
    float acc[7] = {0.f,0.f,0.f,0.f,0.f,0.f,0.f};
    if (k < 4096) {                            // P1  (L=64, quarter=16)
        const float* wr = W3_0 + (size_t)k * 64;
        #pragma unroll
        for (int oo = 0; oo < 16; oo += 4) {
            int o = q*16 + oo;
            float4 wv = *(const float4*)(wr + o);
            const float* w0 = s_wo + o * 7;
            #pragma unroll
            for (int kk = 0; kk < 7; ++kk)
                acc[kk] = fmaf(wv.x, w0[kk], fmaf(wv.y, w0[7+kk],
                          fmaf(wv.z, w0[14+kk], fmaf(wv.w, w0[21+kk], acc[kk]))));
        }
    } else if (k < 10240) {                    // P4  (L=32, quarter=8)
        int it = k >> 6, s = it - 64, m = s >> 5, a2 = s & 31, l = k & 63;
        const float* wr = W3_1 + (size_t)(2048 + a2*64 + l) * 32;
        #pragma unroll
        for (int oo = 0; oo < 8; oo += 4) {
            int o = q*8 + oo;
            float4 wv = *(const float4*)(wr + o);
            const float* w0 = s_wo + (64 + o*3 + m) * 7;
            #pragma unroll
            for (int kk = 0; kk < 7; ++kk)
                acc[kk] = fmaf(wv.x, w0[kk], fmaf(wv.y, w0[21+kk],
                          fmaf(wv.z, w0[42+kk], fmaf(wv.w, w0[63+kk], acc[kk]))));
        }
    } else {
        int it2 = (k - 10240) >> 5, l32 = k & 31;
        if (it2 < 32) {                        // P2  (L=64)
            const float* wr = W3_0 + (size_t)(4096 + it2*32 + l32) * 64;
            #pragma unroll
            for (int oo = 0; oo < 16; oo += 4) {
                int o = q*16 + oo;
                float4 wv = *(const float4*)(wr + o);
                const float* w0 = s_wo + o * 7;
                #pragma unroll
                for (int kk = 0; kk < 7; ++kk)
                    acc[kk] = fmaf(wv.x, w0[kk], fmaf(wv.y, w0[7+kk],
                              fmaf(wv.z, w0[14+kk], fmaf(wv.w, w0[21+kk], acc[kk]))));
            }
        } else if (it2 < 224) {                // P3  (L=32)
            int t = it2 - 32, m = t >> 6, a = t & 63;
            const float* wr = W3_1 + (size_t)(a*32 + l32) * 32;
            #pragma unroll
            for (int oo = 0; oo < 8; oo += 4) {
                int o = q*8 + oo;
                float4 wv = *(const float4*)(wr + o);
                const float* w0 = s_wo + (64 + o*3 + m) * 7;
                #pragma unroll
                for (int kk = 0; kk < 7; ++kk)
                    acc[kk] = fmaf(wv.x, w0[kk], fmaf(wv.y, w0[21+kk],
                              fmaf(wv.z, w0[42+kk], fmaf(wv.w, w0[63+kk], acc[kk]))));
            }
        } else {                               // P5  (L=16, quarter=4)
            int t = it2 - 224, m = t >> 5, a = t & 31;
            const float* wr = W3_2 + (size_t)(a*32 + l32) * 16;
            int o = q*4;
            float4 wv = *(const float4*)(wr + o);
            const float* w0 = s_wo + (160 + o*5 + m) * 7;
            #pragma unroll
            for (int kk = 0; kk < 7; ++kk)
                acc[kk] = fmaf(wv.x, w0[kk], fmaf(wv.y, w0[35+kk],
                          fmaf(wv.z, w0[70+kk], fmaf(wv.w, w0[105+kk], acc[kk]))));
        }
    }
    #pragma unroll
    for (int r = 0; r < 7; ++r) s_red[(q*64 + kl)*8 + r] = acc[r];
    __syncthreads();
    if (tid < 64) {
        int kk2 = blockIdx.x * 64 + tid;
        int e, j;
        if (kk2 < 10240) { e = kk2 / 1280; j = kk2 - e*1280; }
        else { int kb = kk2 - 10240; e = kb / 1536; j = 1280 + kb - e*1536; }
        f16* dst = wsh + e*EI + j;
        #pragma unroll
        for (int r = 0; r < 7; ++r) {
            float v = s_red[(      tid)*8 + r] + s_red[( 64 + tid)*8 + r]
                    + s_red[(128 + tid)*8 + r] + s_red[(192 + tid)*8 + r];
            dst[r*2816] = (f16)v;
        }
    }
}

// ---------------------------------------------------------------------------
// main: 512 blocks x 8 nodes, full K per block (waves split K-chunks).
// Identical to round-4 structure; ONLY change: __launch_bounds__(256, 2)
// (min 2 waves/EU -> VGPR cap 256) so the T14 prefetch regs rg[10] (40 VGPR,
// live across compute) do NOT spill to scratch. Round 4's bare
// __launch_bounds__(256) allocated 68 VGPR and spilled ~160 MB/dispatch
// (WRITE_SIZE=135 MB evidence).
// LDS (47328 B -> 2 blocks/CU at grid 512):
//   [0]      s_g  [7][2832]  f16  39648 B (single buffer; T14 reg prefetch;
//            pad 2832 -> rows 8 banks apart)
//   [39648]  s_uv [8][216]   f16   3456 B (a0|A1|b0|B1|geom|1.0)
//   [43104]  s_ugt[2][88][8] f16   2816 B (u*geom per chunk,node; dbuf)
//   [45920]  s_idx[8][88]    u16   1408 B
//   overlays in s_g area: s_f0[8][64]+s_f1[8][32] f32 (phase N);
//                         s_part[4][8][8] f32 (epilogue)
// ---------------------------------------------------------------------------
__global__ __launch_bounds__(256, 2) void main_kernel(
    const f16* __restrict__ wsh,
    const float* __restrict__ pos,
    const float* __restrict__ W1_0, const float* __restrict__ W1_1,
    const float* __restrict__ W2_0, const float* __restrict__ W2_1,
    const float* __restrict__ bout,
    float* __restrict__ out, int N)
{
    __shared__ __align__(16) char smem[47328];
    f16* s_g   = (f16*)smem;                       // [7][2832]
    f16* s_uv  = (f16*)(smem + 39648);             // [8][216]
    f16* s_ugt = (f16*)(smem + 43104);             // [2][88][8]
    unsigned short* s_idx = (unsigned short*)(smem + 45920);
    float* s_f0 = (float*)smem;                    // [8][64] overlay
    float* s_f1 = (float*)(smem + 2048);           // [8][32] overlay
    (void)N;

    const int tid  = threadIdx.x;
    const int base = blockIdx.x * 8;

    // ---- T14: issue pass-0 G_T loads FIRST; vmcnt wait lands after N0+N1 ----
    uint4 rg[10];
    auto stage_load = [&](int p) {
        const uint4* src = (const uint4*)(wsh + p*EI);   // 39424 B contiguous
        #pragma unroll
        for (int it = 0; it < 10; ++it) {
            int j = tid + it*256;
            if (j < 2464) rg[it] = src[j];
        }
    };
    auto stage_write = [&]() {
        #pragma unroll
        for (int it = 0; it < 10; ++it) {
            int j = tid + it*256;
            if (j < 2464) {
                int row = j / 352, col = j - row*352;
                *(uint4*)(s_g + row*2832 + col*8) = rg[it];
            }
        }
    };
    stage_load(0);

    // ---- phase N0: radial basis + geom + idx table ----
    {
        int d = tid & 63;
        #pragma unroll
        for (int it = 0; it < 2; ++it) {
            int n = (tid >> 6) + it*4;
            const float* pp = pos + (size_t)(base + n) * 3;
            float px = pp[0], py = pp[1], pz = pp[2];
            float r  = sqrtf(px*px + py*py + pz*pz) + 1e-9f;
            float t0 = r - (5.0f/63.0f) * (float)d;
            s_f0[n*64 + d] = __expf(-4.f * t0 * t0);
        }
        {
            int n = tid >> 5, d1 = tid & 31;
            const float* pp = pos + (size_t)(base + n) * 3;
            float px = pp[0], py = pp[1], pz = pp[2];
            float r  = sqrtf(px*px + py*py + pz*pz) + 1e-9f;
            float t1 = r - (5.0f/31.0f) * (float)d1;
            s_f1[n*32 + d1] = __expf(-4.f * t1 * t1);
        }
        if (tid < 8) {
            const float* pp = pos + (size_t)(base + tid) * 3;
            float px = pp[0], py = pp[1], pz = pp[2];
            float r  = sqrtf(px*px + py*py + pz*pz) + 1e-9f;
            float iv = 1.0f / r;
            float d0 = py*iv, dz = pz*iv, dx = px*iv;       // (y,z,x)
            f16* row = s_uv + tid*216;
            row[192+0] = (f16)d0;
            row[192+1] = (f16)dz;
            row[192+2] = (f16)dx;
            row[192+3] = (f16)(NS3 * (d0*d0 + dz*dz + dx*dx));
            row[192+4] = (f16)(2.f*NS2*dx*d0);
            row[192+5] = (f16)(2.f*NS2*d0*dz);
            row[192+6] = (f16)(NS6*(2.f*dz*dz - dx*dx - d0*d0));
            row[192+7] = (f16)(2.f*NS2*dx*dz);
            row[192+8] = (f16)(NS2*(dx*dx - d0*d0));
            row[201]   = (f16)1.0f;
        }
        for (int c = tid; c < 704; c += 256) {      // s_idx, pass-major
            int p  = c / 88, cl = c - p*88;
            int gc = (cl < 40) ? p*40 + cl : 320 + p*48 + (cl - 40);
            int uidx, gidx;
            if (gc < 320) {
                int it = gc >> 1;
                if (it < 64) { uidx = it; gidx = 9; }
                else { int s = it - 64; uidx = 64 + (s & 31); gidx = s >> 5; }
            } else {
                int it2 = gc - 320;
                if (it2 < 32)       { uidx = 64 + it2;                  gidx = 3; }
                else if (it2 < 224) { int t = it2 - 32;  uidx = t & 63;         gidx = t >> 6; }
                else                { int t = it2 - 224; uidx = 64 + (t & 31);  gidx = 4 + (t >> 5); }
            }
            s_idx[c] = (unsigned short)(uidx | (gidx << 8));
        }
    }
    __syncthreads();

    // ---- phase N1: channel-mix GEMMs (fp32) -> s_uv f16 ----
    {
        int c = tid & 63, jb = tid >> 6;
        float a0a = 0.f, a0b = 0.f, b0a = 0.f, b0b = 0.f;
        const float* wa = W1_0 + c;
        const float* wb = W2_0 + c;
        #pragma unroll 4
        for (int d = 0; d < 64; ++d) {
            float wav = wa[d*64], wbv = wb[d*64];
            float fA = s_f0[jb*64 + d], fB = s_f0[(jb+4)*64 + d];
            a0a = fmaf(fA, wav, a0a);  a0b = fmaf(fB, wav, a0b);
            b0a = fmaf(fA, wbv, b0a);  b0b = fmaf(fB, wbv, b0b);
        }
        s_uv[jb*216 +      c] = (f16)a0a;  s_uv[(jb+4)*216 +      c] = (f16)a0b;
        s_uv[jb*216 + 96 + c] = (f16)b0a;  s_uv[(jb+4)*216 + 96 + c] = (f16)b0b;

        int c1 = tid & 31, j8 = tid >> 5;
        float aA = 0.f, aB = 0.f;
        const float* wA = W1_1 + c1;
        const float* wB = W2_1 + c1;
        #pragma unroll 4
        for (int d = 0; d < 32; ++d) {
            float f = s_f1[j8*32 + d];
            aA = fmaf(f, wA[d*32], aA);
            aB = fmaf(f, wB[d*32], aB);
        }
        s_uv[j8*216 +  64 + c1] = (f16)aA;
        s_uv[j8*216 + 160 + c1] = (f16)aB;
    }
    __syncthreads();

    // ---- per-lane constants ----
    const int w    = tid >> 6;
    const int lane = tid & 63;
    const int lq   = lane >> 4;            // k-subrange quarter / D row-group
    const int lm   = lane & 15;            // A row (out-k) / B col (node)
    const int ra   = lm % 7;               // rows 7..15 duplicate (discarded)
    const int nn   = lm & 7;               // cols 8..15 duplicate (discarded)
    const f16* myrow = s_uv + nn*216;
    f16x8 vA0 = *(const f16x8*)(myrow +  96 + lq*8);   // b0[ 0..31]
    f16x8 vA1 = *(const f16x8*)(myrow + 128 + lq*8);   // b0[32..63]
    f16x8 vB  = *(const f16x8*)(myrow + 160 + lq*8);   // B1[ 0..31]

    auto do_ugt = [&](int p, int buf) {
        f16* du = s_ugt + buf*704;
        #pragma unroll
        for (int it = 0; it < 3; ++it) {
            int j = tid + it*256;
            if (j < 704) {
                int cl = j >> 3, n = j & 7;
                unsigned short ix = s_idx[p*88 + cl];
                float u  = (float)s_uv[n*216 + (ix & 255)];
                float gg = (float)s_uv[n*216 + 192 + (ix >> 8)];
                du[cl*8 + n] = (f16)(u * gg);
            }
        }
    };

    f32x4 acc0 = {0.f,0.f,0.f,0.f}, acc1 = {0.f,0.f,0.f,0.f};
    auto compute = [&](int buf) {
        const f16* gb = s_g + ra*2832 + lq*8;
        const f16* ub = s_ugt + buf*704;
        #pragma unroll
        for (int i = 0; i < 10; ++i) {                 // A chunks [w*10,+10)
            int c = w*10 + i;
            f16 ug  = ub[c*8 + nn];
            f16x8 a = *(const f16x8*)(gb + c*32);
            f16x8 vv = (i & 1) ? vA1 : vA0;            // w*10 even -> parity = i&1
            f16x8 b;
            #pragma unroll
            for (int j2 = 0; j2 < 8; ++j2) b[j2] = vv[j2] * ug;
            if (i & 1) acc1 = __builtin_amdgcn_mfma_f32_16x16x32_f16(a, b, acc1, 0, 0, 0);
            else       acc0 = __builtin_amdgcn_mfma_f32_16x16x32_f16(a, b, acc0, 0, 0, 0);
        }
        #pragma unroll
        for (int i = 0; i < 12; ++i) {                 // B chunks [40+w*12,+12)
            int c = 40 + w*12 + i;
            f16 ug  = ub[c*8 + nn];
            f16x8 a = *(const f16x8*)(gb + c*32);
            f16x8 b;
            #pragma unroll
            for (int j2 = 0; j2 < 8; ++j2) b[j2] = vB[j2] * ug;
            if (i & 1) acc1 = __builtin_amdgcn_mfma_f32_16x16x32_f16(a, b, acc1, 0, 0, 0);
            else       acc0 = __builtin_amdgcn_mfma_f32_16x16x32_f16(a, b, acc0, 0, 0, 0);
        }
    };

    // ---- prologue: commit pass 0 (vmcnt wait covered by N0+N1) ----
    stage_write();
    do_ugt(0, 0);
    __syncthreads();

    // ---- 8-pass single-s_g pipeline with T14 reg prefetch ----
    for (int p = 0; p < 8; ++p) {
        int buf = p & 1;
        if (p < 7) { stage_load(p + 1); do_ugt(p + 1, buf ^ 1); }
        compute(buf);
        __syncthreads();                 // all reads of pass-p s_g done
        if (p < 7) {
            stage_write();               // vmcnt wait here (covered by compute)
            __syncthreads();             // pass p+1 visible
        }
    }

    // ---- cross-wave reduce + plain store (bias included) ----
    __syncthreads();                     // s_g free -> s_part overlay
    float* s_part = (float*)smem;        // [4][8][8]
    if (lq < 2 && lm < 8) {
        int nr = (lq == 0) ? 4 : 3;
        for (int r = 0; r < nr; ++r)
            s_part[(w*8 + lm)*8 + lq*4 + r] = acc0[r] + acc1[r];
    }
    __syncthreads();
    if (tid < 56) {
        int n = tid / 7, r = tid - n*7;
        float v = bout[r];
        #pragma unroll
        for (int ww = 0; ww < 4; ++ww) v += s_part[(ww*8 + n)*8 + r];
        out[(size_t)(base + n)*7 + r] = v;
    }
}

extern "C" void kernel_launch(void* const* d_in, const int* in_sizes, int n_in,
                              void* d_out, int out_size, void* d_ws, size_t ws_size,
                              hipStream_t stream)
{
    const float* pos  = (const float*)d_in[0];
    const float* W1_0 = (const float*)d_in[1];
    const float* W1_1 = (const float*)d_in[2];
    const float* W2_0 = (const float*)d_in[3];
    const float* W2_1 = (const float*)d_in[4];
    const float* W3_0 = (const float*)d_in[5];
    const float* W3_1 = (const float*)d_in[6];
    const float* W3_2 = (const float*)d_in[7];
    const float* Wout = (const float*)d_in[8];
    const float* bout = (const float*)d_in[9];
    f16*   wsh = (f16*)d_ws;
    float* op  = (float*)d_out;
    int N = in_sizes[0] / 3;   // 4096

    prep_kernel<<<352, 256, 0, stream>>>(W3_0, W3_1, W3_2, Wout, wsh);
    main_kernel<<<512, 256, 0, stream>>>(wsh, pos, W1_0, W1_1, W2_0, W2_1,
                                         bout, op, N);
}

// Round 7
// 134.740 us; speedup vs baseline: 1.0023x; 1.0023x over previous
//
#include <hip/hip_runtime.h>
#include <math.h>

#define NS2 0.70710678118654752440f  // 1/sqrt(2)
#define NS3 0.57735026918962576451f  // 1/sqrt(3)
#define NS6 0.40824829046386301636f  // 1/sqrt(6)

typedef _Float16 f16;
typedef _Float16 f16x8 __attribute__((ext_vector_type(8)));
typedef float    f32x4 __attribute__((ext_vector_type(4)));

// ws layout: G_T tiled by k-eighth: [8][7][2816] f16 (315.4 KB total).
// Eighth e covers global k: A-part k in [e*1280, +1280) -> local j 0..1279,
// B-part k in [10240 + e*1536, +1536) -> local j 1280..2815.
#define EI 19712          // 7*2816 f16 per eighth

// ---------------------------------------------------------------------------
// prep: G_T build only. 352 blocks x 64 columns. 4 o-split threads per k
// (q = tid>>6), kl = tid&63. LDS: s_wo[1680] + s_red[4][64][8].
// (verbatim — correctness-verified)
// ---------------------------------------------------------------------------
__global__ __launch_bounds__(256) void prep_kernel(
    const float* __restrict__ W3_0, const float* __restrict__ W3_1,
    const float* __restrict__ W3_2, const float* __restrict__ Wout,
    f16* __restrict__ wsh)
{
    __shared__ __align__(16) float smem[3728];
    float* s_wo  = smem;            // Wout 240x7
    float* s_red = smem + 1680;     // [4][64][8] partials
    const int tid = threadIdx.x;
    for (int i = tid; i < 1680; i += 256) s_wo[i] = Wout[i];
    __syncthreads();
    const int kl = tid & 63, q = tid >> 6;
    const int k  = blockIdx.x * 64 + kl;       // 0..22527
    float acc[7] = {0.f,0.f,0.f,0.f,0.f,0.f,0.f};
    if (k < 4096) {                            // P1  (L=64, quarter=16)
        const float* wr = W3_0 + (size_t)k * 64;
        #pragma unroll
        for (int oo = 0; oo < 16; oo += 4) {
            int o = q*16 + oo;
            float4 wv = *(const float4*)(wr + o);
            const float* w0 = s_wo + o * 7;
            #pragma unroll
            for (int kk = 0; kk < 7; ++kk)
                acc[kk] = fmaf(wv.x, w0[kk], fmaf(wv.y, w0[7+kk],
                          fmaf(wv.z, w0[14+kk], fmaf(wv.w, w0[21+kk], acc[kk]))));
        }
    } else if (k < 10240) {                    // P4  (L=32, quarter=8)
        int it = k >> 6, s = it - 64, m = s >> 5, a2 = s & 31, l = k & 63;
        const float* wr = W3_1 + (size_t)(2048 + a2*64 + l) * 32;
        #pragma unroll
        for (int oo = 0; oo < 8; oo += 4) {
            int o = q*8 + oo;
            float4 wv = *(const float4*)(wr + o);
            const float* w0 = s_wo + (64 + o*3 + m) * 7;
            #pragma unroll
            for (int kk = 0; kk < 7; ++kk)
                acc[kk] = fmaf(wv.x, w0[kk], fmaf(wv.y, w0[21+kk],
                          fmaf(wv.z, w0[42+kk], fmaf(wv.w, w0[63+kk], acc[kk]))));
        }
    } else {
        int it2 = (k - 10240) >> 5, l32 = k & 31;
        if (it2 < 32) {                        // P2  (L=64)
            const float* wr = W3_0 + (size_t)(4096 + it2*32 + l32) * 64;
            #pragma unroll
            for (int oo = 0; oo < 16; oo += 4) {
                int o = q*16 + oo;
                float4 wv = *(const float4*)(wr + o);
                const float* w0 = s_wo + o * 7;
                #pragma unroll
                for (int kk = 0; kk < 7; ++kk)
                    acc[kk] = fmaf(wv.x, w0[kk], fmaf(wv.y, w0[7+kk],
                              fmaf(wv.z, w0[14+kk], fmaf(wv.w, w0[21+kk], acc[kk]))));
            }
        } else if (it2 < 224) {                // P3  (L=32)
            int t = it2 - 32, m = t >> 6, a = t & 63;
            const float* wr = W3_1 + (size_t)(a*32 + l32) * 32;
            #pragma unroll
            for (int oo = 0; oo < 8; oo += 4) {
                int o = q*8 + oo;
                float4 wv = *(const float4*)(wr + o);
                const float* w0 = s_wo + (64 + o*3 + m) * 7;
                #pragma unroll
                for (int kk = 0; kk < 7; ++kk)
                    acc[kk] = fmaf(wv.x, w0[kk], fmaf(wv.y, w0[21+kk],
                              fmaf(wv.z, w0[42+kk], fmaf(wv.w, w0[63+kk], acc[kk]))));
            }
        } else {                               // P5  (L=16, quarter=4)
            int t = it2 - 224, m = t >> 5, a = t & 31;
            const float* wr = W3_2 + (size_t)(a*32 + l32) * 16;
            int o = q*4;
            float4 wv = *(const float4*)(wr + o);
            const float* w0 = s_wo + (160 + o*5 + m) * 7;
            #pragma unroll
            for (int kk = 0; kk < 7; ++kk)
                acc[kk] = fmaf(wv.x, w0[kk], fmaf(wv.y, w0[35+kk],
                          fmaf(wv.z, w0[70+kk], fmaf(wv.w, w0[105+kk], acc[kk]))));
        }
    }
    #pragma unroll
    for (int r = 0; r < 7; ++r) s_red[(q*64 + kl)*8 + r] = acc[r];
    __syncthreads();
    if (tid < 64) {
        int kk2 = blockIdx.x * 64 + tid;
        int e, j;
        if (kk2 < 10240) { e = kk2 / 1280; j = kk2 - e*1280; }
        else { int kb = kk2 - 10240; e = kb / 1536; j = 1280 + kb - e*1536; }
        f16* dst = wsh + e*EI + j;
        #pragma unroll
        for (int r = 0; r < 7; ++r) {
            float v = s_red[(      tid)*8 + r] + s_red[( 64 + tid)*8 + r]
                    + s_red[(128 + tid)*8 + r] + s_red[(192 + tid)*8 + r];
            dst[r*2816] = (f16)v;
        }
    }
}

// ---------------------------------------------------------------------------
// main: 512 blocks x 8 nodes, full K per block (waves split K-chunks).
// ONLY change vs round 5: __launch_bounds__(256, 1).
// Evidence: round-3 kernel with the same rg[10] prefetch compiled under
// (256,1) -> VGPR=132, WRITE_SIZE=112 KB (no spill). Bare (256) and (256,2)
// both -> VGPR=68 + 135 MB scratch-spill writes (rounds 4/5; the min-waves
// value acts as an occupancy TARGET for the allocator on this toolchain, and
// only min=1 releases the budget). At ~132 VGPR runtime occupancy is still
// 3 waves/SIMD, and LDS 47.3 KB allows 3 blocks/CU — no occupancy loss.
// LDS (47328 B):
//   [0]      s_g  [7][2832]  f16  39648 B (single buffer; T14 reg prefetch;
//            pad 2832 -> rows 8 banks apart)
//   [39648]  s_uv [8][216]   f16   3456 B (a0|A1|b0|B1|geom|1.0)
//   [43104]  s_ugt[2][88][8] f16   2816 B (u*geom per chunk,node; dbuf)
//   [45920]  s_idx[8][88]    u16   1408 B
//   overlays in s_g area: s_f0[8][64]+s_f1[8][32] f32 (phase N);
//                         s_part[4][8][8] f32 (epilogue)
// ---------------------------------------------------------------------------
__global__ __launch_bounds__(256, 1) void main_kernel(
    const f16* __restrict__ wsh,
    const float* __restrict__ pos,
    const float* __restrict__ W1_0, const float* __restrict__ W1_1,
    const float* __restrict__ W2_0, const float* __restrict__ W2_1,
    const float* __restrict__ bout,
    float* __restrict__ out, int N)
{
    __shared__ __align__(16) char smem[47328];
    f16* s_g   = (f16*)smem;                       // [7][2832]
    f16* s_uv  = (f16*)(smem + 39648);             // [8][216]
    f16* s_ugt = (f16*)(smem + 43104);             // [2][88][8]
    unsigned short* s_idx = (unsigned short*)(smem + 45920);
    float* s_f0 = (float*)smem;                    // [8][64] overlay
    float* s_f1 = (float*)(smem + 2048);           // [8][32] overlay
    (void)N;

    const int tid  = threadIdx.x;
    const int base = blockIdx.x * 8;

    // ---- T14: issue pass-0 G_T loads FIRST; vmcnt wait lands after N0+N1 ----
    uint4 rg[10];
    auto stage_load = [&](int p) {
        const uint4* src = (const uint4*)(wsh + p*EI);   // 39424 B contiguous
        #pragma unroll
        for (int it = 0; it < 10; ++it) {
            int j = tid + it*256;
            if (j < 2464) rg[it] = src[j];
        }
    };
    auto stage_write = [&]() {
        #pragma unroll
        for (int it = 0; it < 10; ++it) {
            int j = tid + it*256;
            if (j < 2464) {
                int row = j / 352, col = j - row*352;
                *(uint4*)(s_g + row*2832 + col*8) = rg[it];
            }
        }
    };
    stage_load(0);

    // ---- phase N0: radial basis + geom + idx table ----
    {
        int d = tid & 63;
        #pragma unroll
        for (int it = 0; it < 2; ++it) {
            int n = (tid >> 6) + it*4;
            const float* pp = pos + (size_t)(base + n) * 3;
            float px = pp[0], py = pp[1], pz = pp[2];
            float r  = sqrtf(px*px + py*py + pz*pz) + 1e-9f;
            float t0 = r - (5.0f/63.0f) * (float)d;
            s_f0[n*64 + d] = __expf(-4.f * t0 * t0);
        }
        {
            int n = tid >> 5, d1 = tid & 31;
            const float* pp = pos + (size_t)(base + n) * 3;
            float px = pp[0], py = pp[1], pz = pp[2];
            float r  = sqrtf(px*px + py*py + pz*pz) + 1e-9f;
            float t1 = r - (5.0f/31.0f) * (float)d1;
            s_f1[n*32 + d1] = __expf(-4.f * t1 * t1);
        }
        if (tid < 8) {
            const float* pp = pos + (size_t)(base + tid) * 3;
            float px = pp[0], py = pp[1], pz = pp[2];
            float r  = sqrtf(px*px + py*py + pz*pz) + 1e-9f;
            float iv = 1.0f / r;
            float d0 = py*iv, dz = pz*iv, dx = px*iv;       // (y,z,x)
            f16* row = s_uv + tid*216;
            row[192+0] = (f16)d0;
            row[192+1] = (f16)dz;
            row[192+2] = (f16)dx;
            row[192+3] = (f16)(NS3 * (d0*d0 + dz*dz + dx*dx));
            row[192+4] = (f16)(2.f*NS2*dx*d0);
            row[192+5] = (f16)(2.f*NS2*d0*dz);
            row[192+6] = (f16)(NS6*(2.f*dz*dz - dx*dx - d0*d0));
            row[192+7] = (f16)(2.f*NS2*dx*dz);
            row[192+8] = (f16)(NS2*(dx*dx - d0*d0));
            row[201]   = (f16)1.0f;
        }
        for (int c = tid; c < 704; c += 256) {      // s_idx, pass-major
            int p  = c / 88, cl = c - p*88;
            int gc = (cl < 40) ? p*40 + cl : 320 + p*48 + (cl - 40);
            int uidx, gidx;
            if (gc < 320) {
                int it = gc >> 1;
                if (it < 64) { uidx = it; gidx = 9; }
                else { int s = it - 64; uidx = 64 + (s & 31); gidx = s >> 5; }
            } else {
                int it2 = gc - 320;
                if (it2 < 32)       { uidx = 64 + it2;                  gidx = 3; }
                else if (it2 < 224) { int t = it2 - 32;  uidx = t & 63;         gidx = t >> 6; }
                else                { int t = it2 - 224; uidx = 64 + (t & 31);  gidx = 4 + (t >> 5); }
            }
            s_idx[c] = (unsigned short)(uidx | (gidx << 8));
        }
    }
    __syncthreads();

    // ---- phase N1: channel-mix GEMMs (fp32) -> s_uv f16 ----
    {
        int c = tid & 63, jb = tid >> 6;
        float a0a = 0.f, a0b = 0.f, b0a = 0.f, b0b = 0.f;
        const float* wa = W1_0 + c;
        const float* wb = W2_0 + c;
        #pragma unroll 4
        for (int d = 0; d < 64; ++d) {
            float wav = wa[d*64], wbv = wb[d*64];
            float fA = s_f0[jb*64 + d], fB = s_f0[(jb+4)*64 + d];
            a0a = fmaf(fA, wav, a0a);  a0b = fmaf(fB, wav, a0b);
            b0a = fmaf(fA, wbv, b0a);  b0b = fmaf(fB, wbv, b0b);
        }
        s_uv[jb*216 +      c] = (f16)a0a;  s_uv[(jb+4)*216 +      c] = (f16)a0b;
        s_uv[jb*216 + 96 + c] = (f16)b0a;  s_uv[(jb+4)*216 + 96 + c] = (f16)b0b;

        int c1 = tid & 31, j8 = tid >> 5;
        float aA = 0.f, aB = 0.f;
        const float* wA = W1_1 + c1;
        const float* wB = W2_1 + c1;
        #pragma unroll 4
        for (int d = 0; d < 32; ++d) {
            float f = s_f1[j8*32 + d];
            aA = fmaf(f, wA[d*32], aA);
            aB = fmaf(f, wB[d*32], aB);
        }
        s_uv[j8*216 +  64 + c1] = (f16)aA;
        s_uv[j8*216 + 160 + c1] = (f16)aB;
    }
    __syncthreads();

    // ---- per-lane constants ----
    const int w    = tid >> 6;
    const int lane = tid & 63;
    const int lq   = lane >> 4;            // k-subrange quarter / D row-group
    const int lm   = lane & 15;            // A row (out-k) / B col (node)
    const int ra   = lm % 7;               // rows 7..15 duplicate (discarded)
    const int nn   = lm & 7;               // cols 8..15 duplicate (discarded)
    const f16* myrow = s_uv + nn*216;
    f16x8 vA0 = *(const f16x8*)(myrow +  96 + lq*8);   // b0[ 0..31]
    f16x8 vA1 = *(const f16x8*)(myrow + 128 + lq*8);   // b0[32..63]
    f16x8 vB  = *(const f16x8*)(myrow + 160 + lq*8);   // B1[ 0..31]

    auto do_ugt = [&](int p, int buf) {
        f16* du = s_ugt + buf*704;
        #pragma unroll
        for (int it = 0; it < 3; ++it) {
            int j = tid + it*256;
            if (j < 704) {
                int cl = j >> 3, n = j & 7;
                unsigned short ix = s_idx[p*88 + cl];
                float u  = (float)s_uv[n*216 + (ix & 255)];
                float gg = (float)s_uv[n*216 + 192 + (ix >> 8)];
                du[cl*8 + n] = (f16)(u * gg);
            }
        }
    };

    f32x4 acc0 = {0.f,0.f,0.f,0.f}, acc1 = {0.f,0.f,0.f,0.f};
    auto compute = [&](int buf) {
        const f16* gb = s_g + ra*2832 + lq*8;
        const f16* ub = s_ugt + buf*704;
        #pragma unroll
        for (int i = 0; i < 10; ++i) {                 // A chunks [w*10,+10)
            int c = w*10 + i;
            f16 ug  = ub[c*8 + nn];
            f16x8 a = *(const f16x8*)(gb + c*32);
            f16x8 vv = (i & 1) ? vA1 : vA0;            // w*10 even -> parity = i&1
            f16x8 b;
            #pragma unroll
            for (int j2 = 0; j2 < 8; ++j2) b[j2] = vv[j2] * ug;
            if (i & 1) acc1 = __builtin_amdgcn_mfma_f32_16x16x32_f16(a, b, acc1, 0, 0, 0);
            else       acc0 = __builtin_amdgcn_mfma_f32_16x16x32_f16(a, b, acc0, 0, 0, 0);
        }
        #pragma unroll
        for (int i = 0; i < 12; ++i) {                 // B chunks [40+w*12,+12)
            int c = 40 + w*12 + i;
            f16 ug  = ub[c*8 + nn];
            f16x8 a = *(const f16x8*)(gb + c*32);
            f16x8 b;
            #pragma unroll
            for (int j2 = 0; j2 < 8; ++j2) b[j2] = vB[j2] * ug;
            if (i & 1) acc1 = __builtin_amdgcn_mfma_f32_16x16x32_f16(a, b, acc1, 0, 0, 0);
            else       acc0 = __builtin_amdgcn_mfma_f32_16x16x32_f16(a, b, acc0, 0, 0, 0);
        }
    };

    // ---- prologue: commit pass 0 (vmcnt wait covered by N0+N1) ----
    stage_write();
    do_ugt(0, 0);
    __syncthreads();

    // ---- 8-pass single-s_g pipeline with T14 reg prefetch ----
    for (int p = 0; p < 8; ++p) {
        int buf = p & 1;
        if (p < 7) { stage_load(p + 1); do_ugt(p + 1, buf ^ 1); }
        compute(buf);
        __syncthreads();                 // all reads of pass-p s_g done
        if (p < 7) {
            stage_write();               // vmcnt wait here (covered by compute)
            __syncthreads();             // pass p+1 visible
        }
    }

    // ---- cross-wave reduce + plain store (bias included) ----
    __syncthreads();                     // s_g free -> s_part overlay
    float* s_part = (float*)smem;        // [4][8][8]
    if (lq < 2 && lm < 8) {
        int nr = (lq == 0) ? 4 : 3;
        for (int r = 0; r < nr; ++r)
            s_part[(w*8 + lm)*8 + lq*4 + r] = acc0[r] + acc1[r];
    }
    __syncthreads();
    if (tid < 56) {
        int n = tid / 7, r = tid - n*7;
        float v = bout[r];
        #pragma unroll
        for (int ww = 0; ww < 4; ++ww) v += s_part[(ww*8 + n)*8 + r];
        out[(size_t)(base + n)*7 + r] = v;
    }
}

extern "C" void kernel_launch(void* const* d_in, const int* in_sizes, int n_in,
                              void* d_out, int out_size, void* d_ws, size_t ws_size,
                              hipStream_t stream)
{
    const float* pos  = (const float*)d_in[0];
    const float* W1_0 = (const float*)d_in[1];
    const float* W1_1 = (const float*)d_in[2];
    const float* W2_0 = (const float*)d_in[3];
    const float* W2_1 = (const float*)d_in[4];
    const float* W3_0 = (const float*)d_in[5];
    const float* W3_1 = (const float*)d_in[6];
    const float* W3_2 = (const float*)d_in[7];
    const float* Wout = (const float*)d_in[8];
    const float* bout = (const float*)d_in[9];
    f16*   wsh = (f16*)d_ws;
    float* op  = (float*)d_out;
    int N = in_sizes[0] / 3;   // 4096

    prep_kernel<<<352, 256, 0, stream>>>(W3_0, W3_1, W3_2, Wout, wsh);
    main_kernel<<<512, 256, 0, stream>>>(wsh, pos, W1_0, W1_1, W2_0, W2_1,
                                         bout, op, N);
}

// Round 8
// 106.986 us; speedup vs baseline: 1.2623x; 1.2594x over previous
//
#include <hip/hip_runtime.h>
#include <math.h>

#define NS2 0.70710678118654752440f  // 1/sqrt(2)
#define NS3 0.57735026918962576451f  // 1/sqrt(3)
#define NS6 0.40824829046386301636f  // 1/sqrt(6)

typedef _Float16 f16;
typedef _Float16 f16x8 __attribute__((ext_vector_type(8)));
typedef float    f32x4 __attribute__((ext_vector_type(4)));

// ws layout: G_T tiled by k-eighth: [8][7][2816] f16 (315.4 KB total).
// Eighth e covers global k: A-part k in [e*1280, +1280) -> local j 0..1279,
// B-part k in [10240 + e*1536, +1536) -> local j 1280..2815.
#define EI 19712          // 7*2816 f16 per eighth

// ---------------------------------------------------------------------------
// prep: G_T build only. 512 blocks x 44 columns (512*44 = 22528 exactly ->
// one block-round over 256 CUs, no tail). 4 o-split threads per k
// (q = tid>>6), kl = tid&63, active for kl < 44.
// LDS: s_wo[1680] + s_red[4][64][8]. (guarded body verified in rounds 1-2)
// ---------------------------------------------------------------------------
__global__ __launch_bounds__(256) void prep_kernel(
    const float* __restrict__ W3_0, const float* __restrict__ W3_1,
    const float* __restrict__ W3_2, const float* __restrict__ Wout,
    f16* __restrict__ wsh)
{
    __shared__ __align__(16) float smem[3728];
    float* s_wo  = smem;            // Wout 240x7
    float* s_red = smem + 1680;     // [4][64][8] partials
    const int tid = threadIdx.x;
    for (int i = tid; i < 1680; i += 256) s_wo[i] = Wout[i];
    __syncthreads();
    const int kl = tid & 63, q = tid >> 6;
    if (kl < 44) {
        const int k = blockIdx.x * 44 + kl;    // 0..22527
        float acc[7] = {0.f,0.f,0.f,0.f,0.f,0.f,0.f};
        if (k < 4096) {                            // P1  (L=64, quarter=16)
            const float* wr = W3_0 + (size_t)k * 64;
            #pragma unroll
            for (int oo = 0; oo < 16; oo += 4) {
                int o = q*16 + oo;
                float4 wv = *(const float4*)(wr + o);
                const float* w0 = s_wo + o * 7;
                #pragma unroll
                for (int kk = 0; kk < 7; ++kk)
                    acc[kk] = fmaf(wv.x, w0[kk], fmaf(wv.y, w0[7+kk],
                              fmaf(wv.z, w0[14+kk], fmaf(wv.w, w0[21+kk], acc[kk]))));
            }
        } else if (k < 10240) {                    // P4  (L=32, quarter=8)
            int it = k >> 6, s = it - 64, m = s >> 5, a2 = s & 31, l = k & 63;
            const float* wr = W3_1 + (size_t)(2048 + a2*64 + l) * 32;
            #pragma unroll
            for (int oo = 0; oo < 8; oo += 4) {
                int o = q*8 + oo;
                float4 wv = *(const float4*)(wr + o);
                const float* w0 = s_wo + (64 + o*3 + m) * 7;
                #pragma unroll
                for (int kk = 0; kk < 7; ++kk)
                    acc[kk] = fmaf(wv.x, w0[kk], fmaf(wv.y, w0[21+kk],
                              fmaf(wv.z, w0[42+kk], fmaf(wv.w, w0[63+kk], acc[kk]))));
            }
        } else {
            int it2 = (k - 10240) >> 5, l32 = k & 31;
            if (it2 < 32) {                        // P2  (L=64)
                const float* wr = W3_0 + (size_t)(4096 + it2*32 + l32) * 64;
                #pragma unroll
                for (int oo = 0; oo < 16; oo += 4) {
                    int o = q*16 + oo;
                    float4 wv = *(const float4*)(wr + o);
                    const float* w0 = s_wo + o * 7;
                    #pragma unroll
                    for (int kk = 0; kk < 7; ++kk)
                        acc[kk] = fmaf(wv.x, w0[kk], fmaf(wv.y, w0[7+kk],
                                  fmaf(wv.z, w0[14+kk], fmaf(wv.w, w0[21+kk], acc[kk]))));
                }
            } else if (it2 < 224) {                // P3  (L=32)
                int t = it2 - 32, m = t >> 6, a = t & 63;
                const float* wr = W3_1 + (size_t)(a*32 + l32) * 32;
                #pragma unroll
                for (int oo = 0; oo < 8; oo += 4) {
                    int o = q*8 + oo;
                    float4 wv = *(const float4*)(wr + o);
                    const float* w0 = s_wo + (64 + o*3 + m) * 7;
                    #pragma unroll
                    for (int kk = 0; kk < 7; ++kk)
                        acc[kk] = fmaf(wv.x, w0[kk], fmaf(wv.y, w0[21+kk],
                                  fmaf(wv.z, w0[42+kk], fmaf(wv.w, w0[63+kk], acc[kk]))));
                }
            } else {                               // P5  (L=16, quarter=4)
                int t = it2 - 224, m = t >> 5, a = t & 31;
                const float* wr = W3_2 + (size_t)(a*32 + l32) * 16;
                int o = q*4;
                float4 wv = *(const float4*)(wr + o);
                const float* w0 = s_wo + (160 + o*5 + m) * 7;
                #pragma unroll
                for (int kk = 0; kk < 7; ++kk)
                    acc[kk] = fmaf(wv.x, w0[kk], fmaf(wv.y, w0[35+kk],
                              fmaf(wv.z, w0[70+kk], fmaf(wv.w, w0[105+kk], acc[kk]))));
            }
        }
        #pragma unroll
        for (int r = 0; r < 7; ++r) s_red[(q*64 + kl)*8 + r] = acc[r];
    }
    __syncthreads();
    if (tid < 44) {
        int kk2 = blockIdx.x * 44 + tid;
        int e, j;
        if (kk2 < 10240) { e = kk2 / 1280; j = kk2 - e*1280; }
        else { int kb = kk2 - 10240; e = kb / 1536; j = 1280 + kb - e*1536; }
        f16* dst = wsh + e*EI + j;
        #pragma unroll
        for (int r = 0; r < 7; ++r) {
            float v = s_red[(      tid)*8 + r] + s_red[( 64 + tid)*8 + r]
                    + s_red[(128 + tid)*8 + r] + s_red[(192 + tid)*8 + r];
            dst[r*2816] = (f16)v;
        }
    }
}

// ---------------------------------------------------------------------------
// main: 512 blocks x 8 nodes, full K per block (waves split K-chunks).
// Change vs rounds 4-7: NO register prefetch across compute. Rounds 4/5/7
// proved the allocator pins VGPR=68 regardless of __launch_bounds__ and
// spills the 40-VGPR rg[10] block to scratch (WRITE_SIZE=135 MB). Staging is
// now immediate load->ds_write in its own barrier region (uint4 live range
// ~2 instructions; compiler pipelines the 10 loads with counted vmcnt).
// Cost: ~1 exposed L2 latency per pass (~1 us total) vs 150 MB scratch I/O.
// LDS (47328 B, 3 blocks/CU by capacity, 2 resident at grid 512):
//   [0]      s_g  [7][2832]  f16  39648 B (pad 2832 -> rows 8 banks apart)
//   [39648]  s_uv [8][216]   f16   3456 B (a0|A1|b0|B1|geom|1.0)
//   [43104]  s_ugt[2][88][8] f16   2816 B (u*geom per chunk,node; dbuf)
//   [45920]  s_idx[8][88]    u16   1408 B
//   overlays in s_g area: s_f0[8][64]+s_f1[8][32] f32 (phase N);
//                         s_part[4][8][8] f32 (epilogue)
// ---------------------------------------------------------------------------
__global__ __launch_bounds__(256, 1) void main_kernel(
    const f16* __restrict__ wsh,
    const float* __restrict__ pos,
    const float* __restrict__ W1_0, const float* __restrict__ W1_1,
    const float* __restrict__ W2_0, const float* __restrict__ W2_1,
    const float* __restrict__ bout,
    float* __restrict__ out, int N)
{
    __shared__ __align__(16) char smem[47328];
    f16* s_g   = (f16*)smem;                       // [7][2832]
    f16* s_uv  = (f16*)(smem + 39648);             // [8][216]
    f16* s_ugt = (f16*)(smem + 43104);             // [2][88][8]
    unsigned short* s_idx = (unsigned short*)(smem + 45920);
    float* s_f0 = (float*)smem;                    // [8][64] overlay
    float* s_f1 = (float*)(smem + 2048);           // [8][32] overlay
    (void)N;

    const int tid  = threadIdx.x;
    const int base = blockIdx.x * 8;

    // ---- phase N0: radial basis + geom + idx table ----
    {
        int d = tid & 63;
        #pragma unroll
        for (int it = 0; it < 2; ++it) {
            int n = (tid >> 6) + it*4;
            const float* pp = pos + (size_t)(base + n) * 3;
            float px = pp[0], py = pp[1], pz = pp[2];
            float r  = sqrtf(px*px + py*py + pz*pz) + 1e-9f;
            float t0 = r - (5.0f/63.0f) * (float)d;
            s_f0[n*64 + d] = __expf(-4.f * t0 * t0);
        }
        {
            int n = tid >> 5, d1 = tid & 31;
            const float* pp = pos + (size_t)(base + n) * 3;
            float px = pp[0], py = pp[1], pz = pp[2];
            float r  = sqrtf(px*px + py*py + pz*pz) + 1e-9f;
            float t1 = r - (5.0f/31.0f) * (float)d1;
            s_f1[n*32 + d1] = __expf(-4.f * t1 * t1);
        }
        if (tid < 8) {
            const float* pp = pos + (size_t)(base + tid) * 3;
            float px = pp[0], py = pp[1], pz = pp[2];
            float r  = sqrtf(px*px + py*py + pz*pz) + 1e-9f;
            float iv = 1.0f / r;
            float d0 = py*iv, dz = pz*iv, dx = px*iv;       // (y,z,x)
            f16* row = s_uv + tid*216;
            row[192+0] = (f16)d0;
            row[192+1] = (f16)dz;
            row[192+2] = (f16)dx;
            row[192+3] = (f16)(NS3 * (d0*d0 + dz*dz + dx*dx));
            row[192+4] = (f16)(2.f*NS2*dx*d0);
            row[192+5] = (f16)(2.f*NS2*d0*dz);
            row[192+6] = (f16)(NS6*(2.f*dz*dz - dx*dx - d0*d0));
            row[192+7] = (f16)(2.f*NS2*dx*dz);
            row[192+8] = (f16)(NS2*(dx*dx - d0*d0));
            row[201]   = (f16)1.0f;
        }
        for (int c = tid; c < 704; c += 256) {      // s_idx, pass-major
            int p  = c / 88, cl = c - p*88;
            int gc = (cl < 40) ? p*40 + cl : 320 + p*48 + (cl - 40);
            int uidx, gidx;
            if (gc < 320) {
                int it = gc >> 1;
                if (it < 64) { uidx = it; gidx = 9; }
                else { int s = it - 64; uidx = 64 + (s & 31); gidx = s >> 5; }
            } else {
                int it2 = gc - 320;
                if (it2 < 32)       { uidx = 64 + it2;                  gidx = 3; }
                else if (it2 < 224) { int t = it2 - 32;  uidx = t & 63;         gidx = t >> 6; }
                else                { int t = it2 - 224; uidx = 64 + (t & 31);  gidx = 4 + (t >> 5); }
            }
            s_idx[c] = (unsigned short)(uidx | (gidx << 8));
        }
    }
    __syncthreads();

    // ---- phase N1: channel-mix GEMMs (fp32) -> s_uv f16 ----
    {
        int c = tid & 63, jb = tid >> 6;
        float a0a = 0.f, a0b = 0.f, b0a = 0.f, b0b = 0.f;
        const float* wa = W1_0 + c;
        const float* wb = W2_0 + c;
        #pragma unroll 4
        for (int d = 0; d < 64; ++d) {
            float wav = wa[d*64], wbv = wb[d*64];
            float fA = s_f0[jb*64 + d], fB = s_f0[(jb+4)*64 + d];
            a0a = fmaf(fA, wav, a0a);  a0b = fmaf(fB, wav, a0b);
            b0a = fmaf(fA, wbv, b0a);  b0b = fmaf(fB, wbv, b0b);
        }
        s_uv[jb*216 +      c] = (f16)a0a;  s_uv[(jb+4)*216 +      c] = (f16)a0b;
        s_uv[jb*216 + 96 + c] = (f16)b0a;  s_uv[(jb+4)*216 + 96 + c] = (f16)b0b;

        int c1 = tid & 31, j8 = tid >> 5;
        float aA = 0.f, aB = 0.f;
        const float* wA = W1_1 + c1;
        const float* wB = W2_1 + c1;
        #pragma unroll 4
        for (int d = 0; d < 32; ++d) {
            float f = s_f1[j8*32 + d];
            aA = fmaf(f, wA[d*32], aA);
            aB = fmaf(f, wB[d*32], aB);
        }
        s_uv[j8*216 +  64 + c1] = (f16)aA;
        s_uv[j8*216 + 160 + c1] = (f16)aB;
    }
    __syncthreads();                     // s_f0/f1 dead; s_g area free

    // ---- per-lane constants ----
    const int w    = tid >> 6;
    const int lane = tid & 63;
    const int lq   = lane >> 4;            // k-subrange quarter / D row-group
    const int lm   = lane & 15;            // A row (out-k) / B col (node)
    const int ra   = lm % 7;               // rows 7..15 duplicate (discarded)
    const int nn   = lm & 7;               // cols 8..15 duplicate (discarded)
    const f16* myrow = s_uv + nn*216;
    f16x8 vA0 = *(const f16x8*)(myrow +  96 + lq*8);   // b0[ 0..31]
    f16x8 vA1 = *(const f16x8*)(myrow + 128 + lq*8);   // b0[32..63]
    f16x8 vB  = *(const f16x8*)(myrow + 160 + lq*8);   // B1[ 0..31]

    // ---- immediate staging: load -> ds_write, short live ranges (no spill) ----
    auto stage = [&](int p) {
        const uint4* src = (const uint4*)(wsh + p*EI);   // 39424 B contiguous
        #pragma unroll
        for (int it = 0; it < 10; ++it) {
            int j = tid + it*256;
            if (j < 2464) {
                uint4 v = src[j];
                int row = j / 352, col = j - row*352;
                *(uint4*)(s_g + row*2832 + col*8) = v;
            }
        }
    };
    auto do_ugt = [&](int p, int buf) {
        f16* du = s_ugt + buf*704;
        #pragma unroll
        for (int it = 0; it < 3; ++it) {
            int j = tid + it*256;
            if (j < 704) {
                int cl = j >> 3, n = j & 7;
                unsigned short ix = s_idx[p*88 + cl];
                float u  = (float)s_uv[n*216 + (ix & 255)];
                float gg = (float)s_uv[n*216 + 192 + (ix >> 8)];
                du[cl*8 + n] = (f16)(u * gg);
            }
        }
    };

    f32x4 acc0 = {0.f,0.f,0.f,0.f}, acc1 = {0.f,0.f,0.f,0.f};
    auto compute = [&](int buf) {
        const f16* gb = s_g + ra*2832 + lq*8;
        const f16* ub = s_ugt + buf*704;
        #pragma unroll
        for (int i = 0; i < 10; ++i) {                 // A chunks [w*10,+10)
            int c = w*10 + i;
            f16 ug  = ub[c*8 + nn];
            f16x8 a = *(const f16x8*)(gb + c*32);
            f16x8 vv = (i & 1) ? vA1 : vA0;            // w*10 even -> parity = i&1
            f16x8 b;
            #pragma unroll
            for (int j2 = 0; j2 < 8; ++j2) b[j2] = vv[j2] * ug;
            if (i & 1) acc1 = __builtin_amdgcn_mfma_f32_16x16x32_f16(a, b, acc1, 0, 0, 0);
            else       acc0 = __builtin_amdgcn_mfma_f32_16x16x32_f16(a, b, acc0, 0, 0, 0);
        }
        #pragma unroll
        for (int i = 0; i < 12; ++i) {                 // B chunks [40+w*12,+12)
            int c = 40 + w*12 + i;
            f16 ug  = ub[c*8 + nn];
            f16x8 a = *(const f16x8*)(gb + c*32);
            f16x8 b;
            #pragma unroll
            for (int j2 = 0; j2 < 8; ++j2) b[j2] = vB[j2] * ug;
            if (i & 1) acc1 = __builtin_amdgcn_mfma_f32_16x16x32_f16(a, b, acc1, 0, 0, 0);
            else       acc0 = __builtin_amdgcn_mfma_f32_16x16x32_f16(a, b, acc0, 0, 0, 0);
        }
    };

    // ---- prologue: stage pass 0 (s_g area free after N1 barrier) ----
    stage(0);
    do_ugt(0, 0);
    __syncthreads();

    // ---- 8-pass pipeline: compute | barrier | stage+ugt | barrier ----
    for (int p = 0; p < 8; ++p) {
        compute(p & 1);
        __syncthreads();                 // all reads of pass-p s_g done
        if (p < 7) {
            stage(p + 1);                // immediate load->write, pipelined
            do_ugt(p + 1, (p & 1) ^ 1);
            __syncthreads();             // pass p+1 visible
        }
    }

    // ---- cross-wave reduce + plain store (bias included) ----
    float* s_part = (float*)smem;        // [4][8][8] overlay (s_g dead)
    if (lq < 2 && lm < 8) {
        int nr = (lq == 0) ? 4 : 3;
        for (int r = 0; r < nr; ++r)
            s_part[(w*8 + lm)*8 + lq*4 + r] = acc0[r] + acc1[r];
    }
    __syncthreads();
    if (tid < 56) {
        int n = tid / 7, r = tid - n*7;
        float v = bout[r];
        #pragma unroll
        for (int ww = 0; ww < 4; ++ww) v += s_part[(ww*8 + n)*8 + r];
        out[(size_t)(base + n)*7 + r] = v;
    }
}

extern "C" void kernel_launch(void* const* d_in, const int* in_sizes, int n_in,
                              void* d_out, int out_size, void* d_ws, size_t ws_size,
                              hipStream_t stream)
{
    const float* pos  = (const float*)d_in[0];
    const float* W1_0 = (const float*)d_in[1];
    const float* W1_1 = (const float*)d_in[2];
    const float* W2_0 = (const float*)d_in[3];
    const float* W2_1 = (const float*)d_in[4];
    const float* W3_0 = (const float*)d_in[5];
    const float* W3_1 = (const float*)d_in[6];
    const float* W3_2 = (const float*)d_in[7];
    const float* Wout = (const float*)d_in[8];
    const float* bout = (const float*)d_in[9];
    f16*   wsh = (f16*)d_ws;
    float* op  = (float*)d_out;
    int N = in_sizes[0] / 3;   // 4096

    prep_kernel<<<512, 256, 0, stream>>>(W3_0, W3_1, W3_2, Wout, wsh);
    main_kernel<<<512, 256, 0, stream>>>(wsh, pos, W1_0, W1_1, W2_0, W2_1,
                                         bout, op, N);
}

// Round 9
// 99.037 us; speedup vs baseline: 1.3636x; 1.0803x over previous
//
#include <hip/hip_runtime.h>
#include <math.h>

#define NS2 0.70710678118654752440f  // 1/sqrt(2)
#define NS3 0.57735026918962576451f  // 1/sqrt(3)
#define NS6 0.40824829046386301636f  // 1/sqrt(6)

typedef _Float16 f16;
typedef _Float16 f16x8 __attribute__((ext_vector_type(8)));
typedef float    f32x4 __attribute__((ext_vector_type(4)));

// ws layout (f16 units) — identical to round-0 baseline:
//   [0]        G_T [7][22528] f16
//   [OFF_UV]   per node [216] f16: a0[0..63] A1[64..95] b0[96..159] B1[160..191]
//              geom[192..200], 1.0 at [201]
#define GT_K    22528
#define UV_ROW  216
#define OFF_UV  157696   // 7*22528

// ---------------------------------------------------------------------------
// G_T build, guarded: 4 o-split threads per k (q = tid>>6), kl = tid&63,
// k = k_base + kl for kl < n_k. LDS: s_wo[1680] + s_red[4][64][8].
// (verified in round-1 phase A with n_k=44)
// ---------------------------------------------------------------------------
__device__ __forceinline__ void build_gt(
    const float* __restrict__ W3_0, const float* __restrict__ W3_1,
    const float* __restrict__ W3_2, const float* __restrict__ Wout,
    f16* __restrict__ wsh, float* smem, int k_base, int n_k)
{
    const int tid = threadIdx.x;
    float* s_wo  = smem;            // Wout 240x7
    float* s_red = smem + 1680;     // [4][64][8] partials
    for (int i = tid; i < 1680; i += 256) s_wo[i] = Wout[i];
    __syncthreads();
    const int kl = tid & 63, q = tid >> 6;
    if (kl < n_k) {
        const int k = k_base + kl;
        float acc[7] = {0.f,0.f,0.f,0.f,0.f,0.f,0.f};
        if (k < 4096) {                            // P1  (L=64, quarter=16)
            const float* wr = W3_0 + (size_t)k * 64;
            #pragma unroll
            for (int oo = 0; oo < 16; oo += 4) {
                int o = q*16 + oo;
                float4 wv = *(const float4*)(wr + o);
                const float* w0 = s_wo + o * 7;
                #pragma unroll
                for (int kk = 0; kk < 7; ++kk)
                    acc[kk] = fmaf(wv.x, w0[kk], fmaf(wv.y, w0[7+kk],
                              fmaf(wv.z, w0[14+kk], fmaf(wv.w, w0[21+kk], acc[kk]))));
            }
        } else if (k < 10240) {                    // P4  (L=32, quarter=8)
            int it = k >> 6, s = it - 64, m = s >> 5, a2 = s & 31, l = k & 63;
            const float* wr = W3_1 + (size_t)(2048 + a2*64 + l) * 32;
            #pragma unroll
            for (int oo = 0; oo < 8; oo += 4) {
                int o = q*8 + oo;
                float4 wv = *(const float4*)(wr + o);
                const float* w0 = s_wo + (64 + o*3 + m) * 7;
                #pragma unroll
                for (int kk = 0; kk < 7; ++kk)
                    acc[kk] = fmaf(wv.x, w0[kk], fmaf(wv.y, w0[21+kk],
                              fmaf(wv.z, w0[42+kk], fmaf(wv.w, w0[63+kk], acc[kk]))));
            }
        } else {
            int it2 = (k - 10240) >> 5, l32 = k & 31;
            if (it2 < 32) {                        // P2  (L=64)
                const float* wr = W3_0 + (size_t)(4096 + it2*32 + l32) * 64;
                #pragma unroll
                for (int oo = 0; oo < 16; oo += 4) {
                    int o = q*16 + oo;
                    float4 wv = *(const float4*)(wr + o);
                    const float* w0 = s_wo + o * 7;
                    #pragma unroll
                    for (int kk = 0; kk < 7; ++kk)
                        acc[kk] = fmaf(wv.x, w0[kk], fmaf(wv.y, w0[7+kk],
                                  fmaf(wv.z, w0[14+kk], fmaf(wv.w, w0[21+kk], acc[kk]))));
                }
            } else if (it2 < 224) {                // P3  (L=32)
                int t = it2 - 32, m = t >> 6, a = t & 63;
                const float* wr = W3_1 + (size_t)(a*32 + l32) * 32;
                #pragma unroll
                for (int oo = 0; oo < 8; oo += 4) {
                    int o = q*8 + oo;
                    float4 wv = *(const float4*)(wr + o);
                    const float* w0 = s_wo + (64 + o*3 + m) * 7;
                    #pragma unroll
                    for (int kk = 0; kk < 7; ++kk)
                        acc[kk] = fmaf(wv.x, w0[kk], fmaf(wv.y, w0[21+kk],
                                  fmaf(wv.z, w0[42+kk], fmaf(wv.w, w0[63+kk], acc[kk]))));
                }
            } else {                               // P5  (L=16, quarter=4)
                int t = it2 - 224, m = t >> 5, a = t & 31;
                const float* wr = W3_2 + (size_t)(a*32 + l32) * 16;
                int o = q*4;
                float4 wv = *(const float4*)(wr + o);
                const float* w0 = s_wo + (160 + o*5 + m) * 7;
                #pragma unroll
                for (int kk = 0; kk < 7; ++kk)
                    acc[kk] = fmaf(wv.x, w0[kk], fmaf(wv.y, w0[35+kk],
                              fmaf(wv.z, w0[70+kk], fmaf(wv.w, w0[105+kk], acc[kk]))));
            }
        }
        #pragma unroll
        for (int r = 0; r < 7; ++r) s_red[(q*64 + kl)*8 + r] = acc[r];
    }
    __syncthreads();
    if (tid < n_k) {
        #pragma unroll
        for (int r = 0; r < 7; ++r) {
            float v = s_red[(      tid)*8 + r] + s_red[( 64 + tid)*8 + r]
                    + s_red[(128 + tid)*8 + r] + s_red[(192 + tid)*8 + r];
            wsh[(size_t)r * GT_K + k_base + tid] = (f16)v;
        }
    }
}

// ---------------------------------------------------------------------------
// Per-node features for 8 nodes starting at `base`. Overlays build_gt's s_wo
// region (safe: s_wo last read before build_gt's 2nd barrier; s_red disjoint).
// (verified in round-1 phase A)
// ---------------------------------------------------------------------------
__device__ __forceinline__ void build_nodes(
    const float* __restrict__ pos,
    const float* __restrict__ W1_0, const float* __restrict__ W1_1,
    const float* __restrict__ W2_0, const float* __restrict__ W2_1,
    const float* __restrict__ bout,
    f16* __restrict__ wsh, float* __restrict__ out, float* smem, int base)
{
    const int tid = threadIdx.x;
    float* s_f0 = smem;          // [8][64]
    float* s_f1 = smem + 512;    // [8][32]
    f16* uv = wsh + OFF_UV;
    {
        int d = tid & 63;
        #pragma unroll
        for (int jj = 0; jj < 2; ++jj) {
            int j = (tid >> 6) + jj * 4;
            int n = base + j;
            float px = pos[n*3+0], py = pos[n*3+1], pz = pos[n*3+2];
            float r  = sqrtf(px*px + py*py + pz*pz) + 1e-9f;
            float t0 = r - (5.0f/63.0f) * (float)d;
            s_f0[j*64 + d] = __expf(-4.f * t0 * t0);
        }
        {
            int j = tid >> 5, d1 = tid & 31;
            int n = base + j;
            float px = pos[n*3+0], py = pos[n*3+1], pz = pos[n*3+2];
            float r  = sqrtf(px*px + py*py + pz*pz) + 1e-9f;
            float t1 = r - (5.0f/31.0f) * (float)d1;
            s_f1[j*32 + d1] = __expf(-4.f * t1 * t1);
        }
        if (tid < 8) {
            int n = base + tid;
            float px = pos[n*3+0], py = pos[n*3+1], pz = pos[n*3+2];
            float r  = sqrtf(px*px + py*py + pz*pz) + 1e-9f;
            float iv = 1.0f / r;
            float d0 = py*iv, d1 = pz*iv, d2 = px*iv;       // (y,z,x)
            f16* row = uv + (size_t)n * UV_ROW;
            row[192+0] = (f16)d0;
            row[192+1] = (f16)d1;
            row[192+2] = (f16)d2;
            row[192+3] = (f16)(NS3 * (d0*d0 + d1*d1 + d2*d2));
            row[192+4] = (f16)(2.f*NS2*d2*d0);
            row[192+5] = (f16)(2.f*NS2*d0*d1);
            row[192+6] = (f16)(NS6*(2.f*d1*d1 - d2*d2 - d0*d0));
            row[192+7] = (f16)(2.f*NS2*d2*d1);
            row[192+8] = (f16)(NS2*(d2*d2 - d0*d0));
            row[201]   = (f16)1.0f;
        }
        if (tid < 56) out[base*7 + tid] = bout[tid % 7];
    }
    __syncthreads();
    {
        int c = tid & 63, jb = tid >> 6;
        float aa0 = 0.f, aa1 = 0.f, ba0 = 0.f, ba1 = 0.f;
        const float* wa = W1_0 + c;
        const float* wb = W2_0 + c;
        #pragma unroll 4
        for (int d = 0; d < 64; ++d) {
            float wav = wa[d*64], wbv = wb[d*64];
            float fA = s_f0[jb*64 + d], fB = s_f0[(jb+4)*64 + d];
            aa0 = fmaf(fA, wav, aa0);  aa1 = fmaf(fB, wav, aa1);
            ba0 = fmaf(fA, wbv, ba0);  ba1 = fmaf(fB, wbv, ba1);
        }
        uv[(size_t)(base+jb  )*UV_ROW +      c] = (f16)aa0;
        uv[(size_t)(base+jb+4)*UV_ROW +      c] = (f16)aa1;
        uv[(size_t)(base+jb  )*UV_ROW + 96 + c] = (f16)ba0;
        uv[(size_t)(base+jb+4)*UV_ROW + 96 + c] = (f16)ba1;

        int c1 = tid & 31, j8 = tid >> 5;
        float aA = 0.f, aB = 0.f;
        const float* wA = W1_1 + c1;
        const float* wB = W2_1 + c1;
        #pragma unroll 4
        for (int d = 0; d < 32; ++d) {
            float f = s_f1[j8*32 + d];
            aA = fmaf(f, wA[d*32], aA);
            aB = fmaf(f, wB[d*32], aB);
        }
        uv[(size_t)(base+j8)*UV_ROW +  64 + c1] = (f16)aA;
        uv[(size_t)(base+j8)*UV_ROW + 160 + c1] = (f16)aB;
    }
}

// prep: 512 blocks, each = 44 G_T columns + 8 nodes (one exact block-round;
// round-0 used 864 blocks = 3.4 CU-rounds with a tail)
__global__ __launch_bounds__(256) void prep_kernel(
    const float* __restrict__ pos,
    const float* __restrict__ W1_0, const float* __restrict__ W1_1,
    const float* __restrict__ W2_0, const float* __restrict__ W2_1,
    const float* __restrict__ W3_0, const float* __restrict__ W3_1,
    const float* __restrict__ W3_2, const float* __restrict__ Wout,
    const float* __restrict__ bout,
    f16* __restrict__ wsh, float* __restrict__ out, int N)
{
    __shared__ __align__(16) float smem[3728];
    (void)N;
    build_gt(W3_0, W3_1, W3_2, Wout, wsh, smem, blockIdx.x * 44, 44);
    build_nodes(pos, W1_0, W1_1, W2_0, W2_1, bout, wsh, out, smem,
                blockIdx.x * 8);
}

// ---------------------------------------------------------------------------
// main: VERBATIM round-0 baseline (measured 96.1-97.8 us total).
// grid = 512: block (g = bi>>3 : 64-node group, kq = bi&7 : K-eighth).
// wave w handles nodes [g*64 + w*16, +16). D = G_T(16 x K) x z(K x 16 nodes);
// A rows 7..15 are a zeroed LDS row (lanes lm>=7 read row 7).
// ---------------------------------------------------------------------------
__global__ __launch_bounds__(256) void main_kernel(
    const f16* __restrict__ wsh, float* __restrict__ out, int N)
{
    __shared__ f16 s_g[2][8][264];         // G_T tile: 7 real rows + zero row 7
    __shared__ f16 s_uv[64][UV_ROW];       // per-node u/v/geom
    __shared__ f16 s_ugt[2][64][8];        // u*geom per (node, chunk-in-tile)
    __shared__ unsigned short s_idx[704];
    (void)N;

    const int tid  = threadIdx.x;
    const int w    = tid >> 6;
    const int lane = tid & 63;
    const int lq   = lane >> 4;            // quad: A/B k-subrange, D row-group
    const int lm   = lane & 15;            // A row (out-k) / B col (node) / D col
    const int ra   = (lm < 7) ? lm : 7;    // A-source row (7 = zero row)
    const int g    = blockIdx.x >> 3;
    const int kq   = blockIdx.x & 7;

    // ---- stage per-node table; compute idx table; zero row 7 of both G bufs ----
    {
        const uint4* src = (const uint4*)(wsh + OFF_UV + (size_t)g * 64 * UV_ROW);
        uint4* dst = (uint4*)&s_uv[0][0];
        for (int j = tid; j < 1728; j += 256) dst[j] = src[j];
        for (int c = tid; c < 704; c += 256) {
            int uidx, gidx;
            if (c < 320) {
                int it = c >> 1;
                if (it < 64) { uidx = it; gidx = 9; }
                else { int s = it - 64; uidx = 64 + (s & 31); gidx = s >> 5; }
            } else {
                int it2 = c - 320;
                if (it2 < 32)       { uidx = 64 + it2;                 gidx = 3; }
                else if (it2 < 224) { int t = it2 - 32;  uidx = t & 63;        gidx = t >> 6; }
                else                { int t = it2 - 224; uidx = 64 + (t & 31); gidx = 4 + (t >> 5); }
            }
            s_idx[c] = (unsigned short)(uidx | (gidx << 8));
        }
        for (int i = tid; i < 264; i += 256) {
            s_g[0][7][i] = (f16)0.f;
            s_g[1][7][i] = (f16)0.f;
        }
    }
    __syncthreads();

    // ---- per-lane constant v-fragments ----
    const f16* myrow = &s_uv[w*16 + lm][0];
    f16x8 vA0 = *(const f16x8*)(myrow +  96 + lq*8);   // b0[ 0..31] slice
    f16x8 vA1 = *(const f16x8*)(myrow + 128 + lq*8);   // b0[32..63] slice
    f16x8 vB  = *(const f16x8*)(myrow + 160 + lq*8);   // B1[ 0..31] slice

    auto c0_of = [&](int t) {
        return (t < 5) ? (kq*40 + t*8) : (320 + kq*48 + (t-5)*8);
    };
    auto stage = [&](int t, int buf) {
        int c0 = c0_of(t), k0 = c0 * 32;
        const f16* src = wsh + k0;
        for (int j = tid; j < 224; j += 256) {          // 7 rows x 256 k (3.5 KB)
            int row = j >> 5, col = j & 31;
            uint4 v = *(const uint4*)(src + (size_t)row * GT_K + col*8);
            *(uint4*)&s_g[buf][row][col*8] = v;
        }
        for (int j = tid; j < 512; j += 256) {          // u*geom per (node, chunk)
            int n = j >> 3, s = j & 7;
            unsigned short ix = s_idx[c0 + s];
            float u  = (float)s_uv[n][ix & 255];
            float gg = (float)s_uv[n][192 + (ix >> 8)];
            s_ugt[buf][n][s] = (f16)(u * gg);
        }
    };

    f32x4 acc = {0.f, 0.f, 0.f, 0.f};
    auto compute = [&](int buf, bool isA) {
        #pragma unroll
        for (int s = 0; s < 8; ++s) {
            f16x8 a = *(const f16x8*)&s_g[buf][ra][s*32 + lq*8];
            f16 ug  = s_ugt[buf][w*16 + lm][s];
            f16x8 vv = isA ? ((s & 1) ? vA1 : vA0) : vB;
            f16x8 b;
            #pragma unroll
            for (int j2 = 0; j2 < 8; ++j2) b[j2] = vv[j2] * ug;
            acc = __builtin_amdgcn_mfma_f32_16x16x32_f16(a, b, acc, 0, 0, 0);
        }
    };

    stage(0, 0);
    __syncthreads();
    for (int t = 0; t < 11; ++t) {
        int buf = t & 1;
        if (t < 10) stage(t + 1, buf ^ 1);
        compute(buf, t < 5);
        __syncthreads();
    }

    // ---- epilogue: D col=lane&15 (node), row=lq*4+reg (out-k); rows 7..15 zero ----
    int node = g*64 + w*16 + lm;
    if (lq == 0) {
        #pragma unroll
        for (int r = 0; r < 4; ++r) atomicAdd(&out[node*7 + r], acc[r]);
    } else if (lq == 1) {
        #pragma unroll
        for (int r = 0; r < 3; ++r) atomicAdd(&out[node*7 + 4 + r], acc[r]);
    }
}

extern "C" void kernel_launch(void* const* d_in, const int* in_sizes, int n_in,
                              void* d_out, int out_size, void* d_ws, size_t ws_size,
                              hipStream_t stream)
{
    const float* pos  = (const float*)d_in[0];
    const float* W1_0 = (const float*)d_in[1];
    const float* W1_1 = (const float*)d_in[2];
    const float* W2_0 = (const float*)d_in[3];
    const float* W2_1 = (const float*)d_in[4];
    const float* W3_0 = (const float*)d_in[5];
    const float* W3_1 = (const float*)d_in[6];
    const float* W3_2 = (const float*)d_in[7];
    const float* Wout = (const float*)d_in[8];
    const float* bout = (const float*)d_in[9];
    f16*   wsh = (f16*)d_ws;
    float* op  = (float*)d_out;
    int N = in_sizes[0] / 3;   // 4096

    prep_kernel<<<512, 256, 0, stream>>>(pos, W1_0, W1_1, W2_0, W2_1,
                                         W3_0, W3_1, W3_2, Wout, bout, wsh, op, N);
    main_kernel<<<512, 256, 0, stream>>>(wsh, op, N);
}